// Round 6
// baseline (94.474 us; speedup 1.0000x reference)
//
#include <hip/hip_runtime.h>

#define G_GEN 65
#define FEAT  8192          // 32*16*16
#define NSTAT 32            // stats blocks
#define NBLK  2048          // total blocks (== exactly full-device residency at 8 blk/CU)
#define MAGIC 0x5A17ED42u

typedef float f32x4 __attribute__((ext_vector_type(4)));

// One kernel, two block roles, device-scope handshake (guide §6 G16).
//  blocks [0,32):    stats -> base rows -> peer count-exchange -> inverse rank map
//  blocks [32,2048): zero-fill contiguous eps chunk -> wait map -> insert own cells
__global__ void __launch_bounds__(256, 8) fused_all(
    const float* __restrict__ x, const float* __restrict__ lambdas,
    int*   __restrict__ rowCol,          // [FEAT]  rank -> feature col (-1 none)
    float* __restrict__ rowVal,          // [FEAT]  rank -> val
    unsigned int* __restrict__ cnt,      // [NSTAT] per-stats-block cross count
    unsigned int* __restrict__ st1,      // [NSTAT] counts-published stamps
    unsigned int* __restrict__ st2,      // [NSTAT] map-published stamps
    float* __restrict__ out)
{
    const int bid = blockIdx.x;
    const int t   = threadIdx.x;

    if (bid < NSTAT) {
        __shared__ int sums[256];
        __shared__ unsigned int scnt[NSTAT];
        const int f = bid * 256 + t;               // this thread's feature
        float c = x[f];                            // generator 0 = center
        float r = 0.f;
        #pragma unroll 8
        for (int g = 1; g < G_GEN; ++g) r += fabsf(x[g * FEAT + f]);
        float l = c - r, u = c + r;
        bool zero_m = (u <= 0.f);
        bool cross  = (!zero_m) && (l < 0.f);
        float d     = u - l;
        float denom = (d > 0.f) ? d : 1.f;
        float slope = u / denom;
        float lam   = lambdas[f];
        float val   = (lam >= slope) ? (-l * lam * 0.5f) : (u * (1.f - lam) * 0.5f);
        val = cross ? val : 0.f;
        float scale = zero_m ? 0.f : (cross ? lam : 1.f);

        // base block rows (overlaps with the big fill on other CUs)
        out[f] = c * scale + val;                  // g == 0 row
        #pragma unroll 8
        for (int g = 1; g < G_GEN; ++g)
            out[g * FEAT + f] = x[g * FEAT + f] * scale;   // 2nd x read: L2-hot

        // intra-block inclusive scan of cross flags
        int flag = cross ? 1 : 0;
        sums[t] = flag;
        __syncthreads();
        for (int off = 1; off < 256; off <<= 1) {
            int v   = sums[t];
            int add = (t >= off) ? sums[t - off] : 0;
            __syncthreads();
            sums[t] = v + add;
            __syncthreads();
        }
        int localRank = sums[t] - flag;            // exclusive local rank
        unsigned int cntB = (unsigned int)sums[255];

        // publish count, then exchange with the 31 peers
        if (t == 0) {
            __hip_atomic_store(&cnt[bid], cntB, __ATOMIC_RELAXED, __HIP_MEMORY_SCOPE_AGENT);
            __hip_atomic_store(&st1[bid], MAGIC, __ATOMIC_RELEASE, __HIP_MEMORY_SCOPE_AGENT);
        }
        if (t < NSTAT) {
            while (__hip_atomic_load(&st1[t], __ATOMIC_RELAXED, __HIP_MEMORY_SCOPE_AGENT) != MAGIC) {}
        }
        __syncthreads();
        (void)__hip_atomic_load(&st1[0], __ATOMIC_ACQUIRE, __HIP_MEMORY_SCOPE_AGENT); // per-thread acquire
        if (t < NSTAT)
            scnt[t] = __hip_atomic_load(&cnt[t], __ATOMIC_RELAXED, __HIP_MEMORY_SCOPE_AGENT);
        __syncthreads();
        unsigned int prefix = 0, nc = 0;
        #pragma unroll
        for (int j = 0; j < NSTAT; ++j) { unsigned int v = scnt[j]; if (j < bid) prefix += v; nc += v; }

        // inverse rank map: slot (prefix+localRank) <- (f, val); tail slots <- -1
        if (cross) {
            rowCol[prefix + localRank] = f;
            rowVal[prefix + localRank] = val;
        }
        if ((unsigned int)f >= nc) rowCol[f] = -1; // slot f has exactly one writer overall
        __syncthreads();                            // all map writes drained (vmcnt) before stamp
        if (t == 0)
            __hip_atomic_store(&st2[bid], MAGIC, __ATOMIC_RELEASE, __HIP_MEMORY_SCOPE_AGENT);
    } else {
        // zero-fill: 16,777,216 float4 over 2016 blocks; q=8322, r=64
        const int  j  = bid - NSTAT;
        const long lo = (long)j * 8322 + (j < 64 ? j : 64);
        const long hi = lo + 8322 + (j < 64 ? 1 : 0);
        f32x4* eps = reinterpret_cast<f32x4*>(out + (size_t)G_GEN * FEAT);
        f32x4 z = {0.f, 0.f, 0.f, 0.f};
        for (long i = lo + t; i < hi; i += 256)
            eps[i] = z;                             // 1 KB/wave contiguous stores
        __syncthreads();                            // zeros drained before inserts

        // wait for the inverse map (stats done ~5us, we finish ~42us: 0 spin iters)
        if (t < NSTAT) {
            while (__hip_atomic_load(&st2[t], __ATOMIC_RELAXED, __HIP_MEMORY_SCOPE_AGENT) != MAGIC) {}
        }
        __syncthreads();
        (void)__hip_atomic_load(&st2[0], __ATOMIC_ACQUIRE, __HIP_MEMORY_SCOPE_AGENT); // per-thread acquire

        // insert scatter cells whose f4 index lies in [lo,hi): rank k occupies
        // f4 range [k*2048, k*2048+2047] -> <=6 candidate ranks per chunk
        long kmin = (lo > 2047) ? ((lo - 2047) >> 11) : 0;
        long kmax = (hi - 1) >> 11;
        long k = kmin + t;
        if (k <= kmax) {
            int col = rowCol[k];
            if (col >= 0) {
                long f4 = (k << 11) + (col >> 2);
                if (f4 >= lo && f4 < hi)
                    out[(size_t)(G_GEN + k) * FEAT + col] = rowVal[k];
            }
        }
    }
}

extern "C" void kernel_launch(void* const* d_in, const int* in_sizes, int n_in,
                              void* d_out, int out_size, void* d_ws, size_t ws_size,
                              hipStream_t stream) {
    const float* x       = (const float*)d_in[0];
    const float* lambdas = (const float*)d_in[1];
    float* out = (float*)d_out;

    int*          rowCol = (int*)d_ws;                       // 32 KB
    float*        rowVal = (float*)(rowCol + FEAT);          // 32 KB
    unsigned int* cnt    = (unsigned int*)(rowVal + FEAT);   // 128 B
    unsigned int* st1    = cnt + NSTAT;                      // 128 B
    unsigned int* st2    = st1 + NSTAT;                      // 128 B

    fused_all<<<NBLK, 256, 0, stream>>>(x, lambdas, rowCol, rowVal, cnt, st1, st2, out);
}